// Round 3
// baseline (1450.166 us; speedup 1.0000x reference)
//
#include <hip/hip_runtime.h>

#define HID 128
#define ODIM 64

typedef _Float16 half8 __attribute__((ext_vector_type(8)));
typedef float f32x4 __attribute__((ext_vector_type(4)));

// ---------------------------------------------------------------------------
// k_prep: split all GEMM weights into f16 hi/lo planes ONCE, transposed to
// [n][k], K-chunked, rows padded to stride 40 halves (conflict-free b128).
// Layouts (in halves):
//   WspHi: [L=4][kc=4][n=128][40]   offset 0       (81920)
//   WspLo: [L=4][kc=4][n=128][40]   offset 81920   (81920)
//   WhHi : [kc=4][n=64][40]         offset 163840  (10240)
//   WhLo : [kc=4][n=64][40]         offset 174080  (10240)
// Total 184320 halves = 368640 B of workspace.
// ---------------------------------------------------------------------------
__global__ __launch_bounds__(256) void k_prep(
    const float* __restrict__ Wg, const float* __restrict__ Wout,
    _Float16* __restrict__ WspHi, _Float16* __restrict__ WspLo,
    _Float16* __restrict__ WhHi, _Float16* __restrict__ WhLo) {
  int i = blockIdx.x * 256 + threadIdx.x;
  if (i < 81920) {  // hidden hi
    int kp = i % 40, n = (i / 40) & 127, kc = (i / 5120) & 3, l = i / 20480;
    float v = kp < 32 ? Wg[(size_t)(l * 128 + kc * 32 + kp) * 128 + n] : 0.f;
    WspHi[i] = (_Float16)v;
  } else if (i < 163840) {  // hidden lo
    int j = i - 81920;
    int kp = j % 40, n = (j / 40) & 127, kc = (j / 5120) & 3, l = j / 20480;
    float v = kp < 32 ? Wg[(size_t)(l * 128 + kc * 32 + kp) * 128 + n] : 0.f;
    _Float16 h = (_Float16)v;
    WspLo[j] = (_Float16)(v - (float)h);
  } else if (i < 174080) {  // head hi
    int j = i - 163840;
    int kp = j % 40, n = (j / 40) & 63, kc = j / 2560;
    float v = kp < 32 ? Wout[(kc * 32 + kp) * 64 + n] : 0.f;
    WhHi[j] = (_Float16)v;
  } else if (i < 184320) {  // head lo
    int j = i - 174080;
    int kp = j % 40, n = (j / 40) & 63, kc = j / 2560;
    float v = kp < 32 ? Wout[(kc * 32 + kp) * 64 + n] : 0.f;
    _Float16 h = (_Float16)v;
    WhLo[j] = (_Float16)(v - (float)h);
  }
}

// ---------------------------------------------------------------------------
// Fused GCN layer v4: Xout = relu(LN((A·X)@W + bg)) + X
//  - T14 async-STAGE: prefetch kc+1's X tile + W chunk into registers before
//    computing kc; HBM latency hides under the MFMA/stencil phase instead of
//    being drained at the barrier (v3 was latency-bound: no pipe >36% busy).
//  - ENC=true additionally fuses the encoder: X0 is computed on the fly from
//    grids+Win during staging (no X0 read) and recomputed for the residual in
//    the epilogue (no X0 buffer at all -> saves ~500 MB of HBM traffic).
// ---------------------------------------------------------------------------
template <bool ENC>
__global__ __launch_bounds__(512, 4) void k_hidden_t(
    const float* __restrict__ Xin, float* __restrict__ Xout,
    const _Float16* __restrict__ Whi, const _Float16* __restrict__ Wlo,
    const float* __restrict__ bgp, const float* __restrict__ gamp,
    const float* __restrict__ betp, const int* __restrict__ grids,
    const float* __restrict__ Win, const float* __restrict__ binp,
    int b0n, int nodesTotal) {
  constexpr int XTS = 36;    // Xt row stride in dwords (16B rows, 2-way alias = free)
  constexpr int XROWS = 316; // 256 + 2*30 halo
  __shared__ __attribute__((aligned(16))) float Xt[XROWS * XTS];    // 45504 B
  __shared__ __attribute__((aligned(16))) _Float16 WThi[128 * 40];  // 10240 B
  __shared__ __attribute__((aligned(16))) _Float16 WTlo[128 * 40];  // 10240 B

  const int t = threadIdx.x;
  const int lane = t & 63;
  const int wave = t >> 6;
  const int q = lane >> 4, l16 = lane & 15;
  const int blockRow0 = blockIdx.x * 256;
  const int waveRow0 = blockRow0 + wave * 32;

  // Stencil: one LDS base per M-tile (corner = up-neighbor row), neighbors via
  // compile-time dword offsets: up=0, left=1044, self=1080, right=1116,
  // down=2160. Invalid directions get weight 0 (staged data is clamped-finite).
  int xb[2];
  float wts[2][5];
#pragma unroll
  for (int mt = 0; mt < 2; ++mt) {
    int nd = waveRow0 + mt * 16 + l16;
    if (nd > nodesTotal - 1) nd = nodesTotal - 1;
    int n = nd % 900;
    int r = n / 30, c = n - r * 30;
    int loc = nd - blockRow0 + 30;  // in [30, 285]
    xb[mt] = (loc - 30) * XTS;
    float dc = rsqrtf((float)(1 + (r > 0) + (r < 29) + (c > 0) + (c < 29)));
    wts[mt][0] = dc * dc;
    wts[mt][1] = (r > 0) ? dc * rsqrtf((float)(2 + (r > 1) + (c > 0) + (c < 29))) : 0.f;
    wts[mt][2] = (r < 29) ? dc * rsqrtf((float)(2 + (r < 28) + (c > 0) + (c < 29))) : 0.f;
    wts[mt][3] = (c > 0) ? dc * rsqrtf((float)(2 + (r > 0) + (r < 29) + (c > 1))) : 0.f;
    wts[mt][4] = (c < 29) ? dc * rsqrtf((float)(2 + (r > 0) + (r < 29) + (c < 28))) : 0.f;
  }

  f32x4 acc[2][8];
#pragma unroll
  for (int mt = 0; mt < 2; ++mt)
#pragma unroll
    for (int nt = 0; nt < 8; ++nt) acc[mt][nt] = (f32x4){0.f, 0.f, 0.f, 0.f};

  // ---- staging registers (T14): 5 X granules + 2+2 W granules per thread
  f32x4 xr[5], wh[2], wl[2];

  auto prefetch = [&](int kc) {
#pragma unroll
    for (int s = 0; s < 5; ++s) {
      if (s == 4 && t >= 480) continue;  // XROWS*8 = 2528 = 4*512 + 480
      int f = t + s * 512;
      int row = f >> 3, v = f & 7;
      int gr = blockRow0 - 30 + row;
      gr = gr < 0 ? 0 : (gr > nodesTotal - 1 ? nodesTotal - 1 : gr);
      if (ENC) {
        int color = grids[b0n + gr];
        int n = gr % 900;
        int rr = n / 30, cc = n - rr * 30;
        float fr = rr * (1.f / 29.f), fc = cc * (1.f / 29.f);
        f32x4 wc = ((const f32x4*)(Win + color * HID))[kc * 8 + v];
        f32x4 wr = ((const f32x4*)(Win + 10 * HID))[kc * 8 + v];
        f32x4 wlv = ((const f32x4*)(Win + 11 * HID))[kc * 8 + v];
        f32x4 bb = ((const f32x4*)binp)[kc * 8 + v];
        f32x4 vv = wc + fr * wr + fc * wlv + bb;
#pragma unroll
        for (int j = 0; j < 4; ++j) vv[j] = fmaxf(vv[j], 0.0f);
        xr[s] = vv;
      } else {
        xr[s] = *(const f32x4*)(Xin + (size_t)gr * HID + kc * 32 + v * 4);
      }
    }
    wh[0] = ((const f32x4*)(Whi + kc * 5120))[t];  // 640 granules/plane/chunk
    if (t < 128) wh[1] = ((const f32x4*)(Whi + kc * 5120))[t + 512];
    wl[0] = ((const f32x4*)(Wlo + kc * 5120))[t];
    if (t < 128) wl[1] = ((const f32x4*)(Wlo + kc * 5120))[t + 512];
  };

  auto writeLDS = [&]() {
#pragma unroll
    for (int s = 0; s < 5; ++s) {
      if (s == 4 && t >= 480) continue;
      int f = t + s * 512;
      int row = f >> 3, v = f & 7;
      *(f32x4*)(Xt + row * XTS + v * 4) = xr[s];
    }
    ((f32x4*)WThi)[t] = wh[0];
    if (t < 128) ((f32x4*)WThi)[t + 512] = wh[1];
    ((f32x4*)WTlo)[t] = wl[0];
    if (t < 128) ((f32x4*)WTlo)[t + 512] = wl[1];
  };

  prefetch(0);
  for (int kc = 0; kc < 4; ++kc) {
    __syncthreads();  // previous iteration's LDS fully consumed
    writeLDS();
    if (kc < 3) prefetch(kc + 1);  // lands during compute below
    __syncthreads();

    // ---- A fragments: 5-point stencil from LDS, split f16 hi/lo
    half8 Ahi[2], Alo[2];
#pragma unroll
    for (int mt = 0; mt < 2; ++mt) {
      const float* x0 = Xt + xb[mt] + q * 8;
      f32x4 s0 = wts[mt][0] * (*(const f32x4*)(x0 + 1080));
      f32x4 s1 = wts[mt][0] * (*(const f32x4*)(x0 + 1084));
      s0 += wts[mt][1] * (*(const f32x4*)(x0 + 0));
      s1 += wts[mt][1] * (*(const f32x4*)(x0 + 4));
      s0 += wts[mt][2] * (*(const f32x4*)(x0 + 2160));
      s1 += wts[mt][2] * (*(const f32x4*)(x0 + 2164));
      s0 += wts[mt][3] * (*(const f32x4*)(x0 + 1044));
      s1 += wts[mt][3] * (*(const f32x4*)(x0 + 1048));
      s0 += wts[mt][4] * (*(const f32x4*)(x0 + 1116));
      s1 += wts[mt][4] * (*(const f32x4*)(x0 + 1120));
#pragma unroll
      for (int j = 0; j < 4; ++j) {
        _Float16 h0 = (_Float16)s0[j];
        Ahi[mt][j] = h0;
        Alo[mt][j] = (_Float16)(s0[j] - (float)h0);
        _Float16 h1 = (_Float16)s1[j];
        Ahi[mt][4 + j] = h1;
        Alo[mt][4 + j] = (_Float16)(s1[j] - (float)h1);
      }
    }
    // ---- B fragments + MFMA (both planes stride 40 -> single b128 reads)
    const int kb = q * 8;
#pragma unroll
    for (int nt = 0; nt < 8; ++nt) {
      int n = nt * 16 + l16;
      half8 bhi = *(const half8*)(WThi + n * 40 + kb);
      half8 blo = *(const half8*)(WTlo + n * 40 + kb);
#pragma unroll
      for (int mt = 0; mt < 2; ++mt) {
        acc[mt][nt] = __builtin_amdgcn_mfma_f32_16x16x32_f16(Alo[mt], bhi, acc[mt][nt], 0, 0, 0);
        acc[mt][nt] = __builtin_amdgcn_mfma_f32_16x16x32_f16(Ahi[mt], blo, acc[mt][nt], 0, 0, 0);
        acc[mt][nt] = __builtin_amdgcn_mfma_f32_16x16x32_f16(Ahi[mt], bhi, acc[mt][nt], 0, 0, 0);
      }
    }
  }

  // ---- epilogue: bias + LN + relu + residual, direct store from C/D layout
  float bgv[8], gv[8], btv[8];
#pragma unroll
  for (int nt = 0; nt < 8; ++nt) {
    int cl = nt * 16 + l16;
    bgv[nt] = bgp[cl];
    gv[nt] = gamp[cl];
    btv[nt] = betp[cl];
  }
  float w10c[8], w11c[8], bbc[8];
  if (ENC) {
#pragma unroll
    for (int nt = 0; nt < 8; ++nt) {
      int cl = nt * 16 + l16;
      w10c[nt] = Win[10 * HID + cl];
      w11c[nt] = Win[11 * HID + cl];
      bbc[nt] = binp[cl];
    }
  }
#pragma unroll
  for (int mt = 0; mt < 2; ++mt) {
#pragma unroll
    for (int reg = 0; reg < 4; ++reg) {
      float rs = 0.f;
#pragma unroll
      for (int nt = 0; nt < 8; ++nt) {
        acc[mt][nt][reg] += bgv[nt];
        rs += acc[mt][nt][reg];
      }
      rs += __shfl_xor(rs, 1, 64);
      rs += __shfl_xor(rs, 2, 64);
      rs += __shfl_xor(rs, 4, 64);
      rs += __shfl_xor(rs, 8, 64);
      float mean = rs * (1.f / 128.f);
      float ss = 0.f;
#pragma unroll
      for (int nt = 0; nt < 8; ++nt) {
        float d = acc[mt][nt][reg] - mean;
        ss += d * d;
      }
      ss += __shfl_xor(ss, 1, 64);
      ss += __shfl_xor(ss, 2, 64);
      ss += __shfl_xor(ss, 4, 64);
      ss += __shfl_xor(ss, 8, 64);
      float rsd = rsqrtf(ss * (1.f / 128.f) + 1e-5f);
      int row = waveRow0 + mt * 16 + q * 4 + reg;  // uniform across the 16-lane group
      if (row < nodesTotal) {
        float* xo = Xout + (size_t)row * HID;
        if (ENC) {
          int n = row % 900;
          int rr = n / 30, cc = n - rr * 30;
          float fr = rr * (1.f / 29.f), fc = cc * (1.f / 29.f);
          const float* wcp = Win + grids[b0n + row] * HID;
#pragma unroll
          for (int nt = 0; nt < 8; ++nt) {
            int col = nt * 16 + l16;
            float y = fmaxf((acc[mt][nt][reg] - mean) * rsd * gv[nt] + btv[nt], 0.f);
            float x0 = fmaxf(wcp[col] + fr * w10c[nt] + fc * w11c[nt] + bbc[nt], 0.f);
            xo[col] = y + x0;
          }
        } else {
          const float* xr = Xin + (size_t)row * HID;
#pragma unroll
          for (int nt = 0; nt < 8; ++nt) {
            int col = nt * 16 + l16;
            float y = fmaxf((acc[mt][nt][reg] - mean) * rsd * gv[nt] + btv[nt], 0.f);
            xo[col] = y + xr[col];
          }
        }
      }
    }
  }
}

// ---------------------------------------------------------------------------
// Head v4: Out = Xin @ Wout + bout (pre-split W, M=256, T14 prefetch)
// ---------------------------------------------------------------------------
__global__ __launch_bounds__(512, 4) void k_head(
    const float* __restrict__ Xin, float* __restrict__ Out,
    const _Float16* __restrict__ Whi, const _Float16* __restrict__ Wlo,
    const float* __restrict__ bp, int nodesTotal) {
  constexpr int XTS = 36;
  __shared__ __attribute__((aligned(16))) float Xt[256 * XTS];     // 36864 B
  __shared__ __attribute__((aligned(16))) _Float16 WThi[64 * 40];  //  5120 B
  __shared__ __attribute__((aligned(16))) _Float16 WTlo[64 * 40];  //  5120 B

  const int t = threadIdx.x;
  const int lane = t & 63;
  const int wave = t >> 6;
  const int q = lane >> 4, l16 = lane & 15;
  const int blockRow0 = blockIdx.x * 256;
  const int waveRow0 = blockRow0 + wave * 32;

  int xb[2];
#pragma unroll
  for (int mt = 0; mt < 2; ++mt) {
    int nd = waveRow0 + mt * 16 + l16;
    if (nd > nodesTotal - 1) nd = nodesTotal - 1;
    xb[mt] = (nd - blockRow0) * XTS;
  }

  f32x4 acc[2][4];
#pragma unroll
  for (int mt = 0; mt < 2; ++mt)
#pragma unroll
    for (int nt = 0; nt < 4; ++nt) acc[mt][nt] = (f32x4){0.f, 0.f, 0.f, 0.f};

  f32x4 xr[4], wh, wl;

  auto prefetch = [&](int kc) {
#pragma unroll
    for (int s = 0; s < 4; ++s) {  // 256*8 = 2048 = 4*512 exactly
      int f = t + s * 512;
      int row = f >> 3, v = f & 7;
      int gr = blockRow0 + row;
      if (gr > nodesTotal - 1) gr = nodesTotal - 1;
      xr[s] = *(const f32x4*)(Xin + (size_t)gr * HID + kc * 32 + v * 4);
    }
    if (t < 320) {  // 64*40 halves = 320 granules/plane/chunk
      wh = ((const f32x4*)(Whi + kc * 2560))[t];
      wl = ((const f32x4*)(Wlo + kc * 2560))[t];
    }
  };

  auto writeLDS = [&]() {
#pragma unroll
    for (int s = 0; s < 4; ++s) {
      int f = t + s * 512;
      int row = f >> 3, v = f & 7;
      *(f32x4*)(Xt + row * XTS + v * 4) = xr[s];
    }
    if (t < 320) {
      ((f32x4*)WThi)[t] = wh;
      ((f32x4*)WTlo)[t] = wl;
    }
  };

  prefetch(0);
  for (int kc = 0; kc < 4; ++kc) {
    __syncthreads();
    writeLDS();
    if (kc < 3) prefetch(kc + 1);
    __syncthreads();

    half8 Ahi[2], Alo[2];
#pragma unroll
    for (int mt = 0; mt < 2; ++mt) {
      const float* xp = Xt + xb[mt] + q * 8;
      f32x4 s0 = *(const f32x4*)xp;
      f32x4 s1 = *(const f32x4*)(xp + 4);
#pragma unroll
      for (int j = 0; j < 4; ++j) {
        _Float16 h0 = (_Float16)s0[j];
        Ahi[mt][j] = h0;
        Alo[mt][j] = (_Float16)(s0[j] - (float)h0);
        _Float16 h1 = (_Float16)s1[j];
        Ahi[mt][4 + j] = h1;
        Alo[mt][4 + j] = (_Float16)(s1[j] - (float)h1);
      }
    }
    const int kb = q * 8;
#pragma unroll
    for (int nt = 0; nt < 4; ++nt) {
      int n = nt * 16 + l16;
      half8 bhi = *(const half8*)(WThi + n * 40 + kb);
      half8 blo = *(const half8*)(WTlo + n * 40 + kb);
#pragma unroll
      for (int mt = 0; mt < 2; ++mt) {
        acc[mt][nt] = __builtin_amdgcn_mfma_f32_16x16x32_f16(Alo[mt], bhi, acc[mt][nt], 0, 0, 0);
        acc[mt][nt] = __builtin_amdgcn_mfma_f32_16x16x32_f16(Ahi[mt], blo, acc[mt][nt], 0, 0, 0);
        acc[mt][nt] = __builtin_amdgcn_mfma_f32_16x16x32_f16(Ahi[mt], bhi, acc[mt][nt], 0, 0, 0);
      }
    }
  }

  float bv[4];
#pragma unroll
  for (int nt = 0; nt < 4; ++nt) bv[nt] = bp[nt * 16 + l16];
#pragma unroll
  for (int mt = 0; mt < 2; ++mt) {
#pragma unroll
    for (int reg = 0; reg < 4; ++reg) {
      int row = waveRow0 + mt * 16 + q * 4 + reg;
      if (row < nodesTotal) {
        float* op = Out + (size_t)row * ODIM;
#pragma unroll
        for (int nt = 0; nt < 4; ++nt)
          op[nt * 16 + l16] = acc[mt][nt][reg] + bv[nt];
      }
    }
  }
}

// ---------------------------------------------------------------------------
extern "C" void kernel_launch(void* const* d_in, const int* in_sizes, int n_in,
                              void* d_out, int out_size, void* d_ws, size_t ws_size,
                              hipStream_t stream) {
  const int* grids = (const int*)d_in[0];
  // d_in[1] = edge_index: unused (fixed 30x30 grid + self-loops, analytic coefs)
  const float* Win  = (const float*)d_in[2];
  const float* bin  = (const float*)d_in[3];
  const float* Wg   = (const float*)d_in[4];
  const float* bg   = (const float*)d_in[5];
  const float* gam  = (const float*)d_in[6];
  const float* bet  = (const float*)d_in[7];
  const float* Wout = (const float*)d_in[8];
  const float* bout = (const float*)d_in[9];
  float* Out = (float*)d_out;

  // workspace: [pre-split W (368640 B) | Xa | Xb]
  _Float16* WspHi = (_Float16*)d_ws;
  _Float16* WspLo = WspHi + 81920;
  _Float16* WhHi  = WspHi + 163840;
  _Float16* WhLo  = WspHi + 174080;
  const size_t wBytes = 368640;

  const int Btot = 512;
  const size_t perBatchBytes = (size_t)900 * HID * 4 * 2;  // ping-pong X buffers
  size_t xws = ws_size > wBytes ? ws_size - wBytes : 0;
  int chunkB = (int)(xws / perBatchBytes);
  if (chunkB > Btot) chunkB = Btot;
  if (chunkB < 1) chunkB = 1;
  int nch = (Btot + chunkB - 1) / chunkB;

  float* Xa = (float*)((char*)d_ws + wBytes);
  float* Xb = Xa + (size_t)chunkB * 900 * HID;

  k_prep<<<dim3(720), dim3(256), 0, stream>>>(Wg, Wout, WspHi, WspLo, WhHi, WhLo);

  for (int ci = 0; ci < nch; ++ci) {
    int b0 = ci * chunkB;
    int cb = Btot - b0;
    if (cb > chunkB) cb = chunkB;
    int nodes = cb * 900;
    int b0n = b0 * 900;
    int gb = (nodes + 255) / 256;

    // layer 0 with fused encoder: grids -> Xa (no X0 buffer ever materialized)
    k_hidden_t<true><<<dim3(gb), dim3(512), 0, stream>>>(
        Xb, Xa, WspHi, WspLo, bg, gam, bet, grids, Win, bin, b0n, nodes);
    // layers 1..3: Xa->Xb->Xa->Xb
    float* src = Xa;
    float* dst = Xb;
    for (int l = 1; l < 4; ++l) {
      k_hidden_t<false><<<dim3(gb), dim3(512), 0, stream>>>(
          src, dst, WspHi + l * 20480, WspLo + l * 20480,
          bg + l * HID, gam + l * HID, bet + l * HID, grids, Win, bin, b0n, nodes);
      float* tmp = src; src = dst; dst = tmp;
    }
    // after layers 1..3 the final X is in Xb (src points at it post-swap)
    k_head<<<dim3(gb), dim3(512), 0, stream>>>(
        src, Out + (size_t)b0 * 900 * ODIM, WhHi, WhLo, bout, nodes);
  }
}